// Round 1
// baseline (502.158 us; speedup 1.0000x reference)
//
#include <hip/hip_runtime.h>

// Swin shifted-window attention, fused. B=32, C=256, H=W=64, WIN=8, SHIFT=4,
// HEADS=8, HD=32, N=64 tokens/window.
// v2: TWO windows per block (512 thr, 8 waves) -> weight staging amortized 2x,
//     occupancy 16 waves/CU (was 8); DPP softmax reductions (VALU pipe, not
//     ds_bpermute); lgkm-only barriers (global stores overlap next head);
//     mask/rel-idx hoisted out of the head loop. LDS strides preserved from
//     the verified 455us kernel (odd 16B-unit strides = conflict-free b128).

typedef __attribute__((ext_vector_type(8))) short short8;   // 8 x bf16 (4 VGPR)
typedef __attribute__((ext_vector_type(4))) float f32x4;

static __device__ __forceinline__ short f2bf(float f) {
    unsigned u = __float_as_uint(f);
    u = (u + 0x7fffu + ((u >> 16) & 1u)) >> 16;   // round-to-nearest-even
    return (short)u;
}

static __device__ __forceinline__ int region(int i) {
    // shift-mask region along one axis: [0,56)=0, [56,60)=1, [60,64)=2
    return (i < 56) ? 0 : ((i < 60) ? 1 : 2);
}

// Barrier that only waits on LDS (lgkmcnt). __syncthreads() would force
// vmcnt(0) too, draining the per-head global stores. All cross-wave deps at
// our barriers are LDS-only, so lgkmcnt(0) suffices. asm memory clobbers on
// both sides keep the compiler from moving LDS ops across the barrier.
static __device__ __forceinline__ void barrier_lds() {
    asm volatile("s_waitcnt lgkmcnt(0)" ::: "memory");
    __builtin_amdgcn_s_barrier();
    asm volatile("" ::: "memory");
}

// Butterfly reduction over 16 lanes (one DPP row) on the VALU pipe.
// xor1/xor2 via quad_perm; after value is 4-uniform, row_half_mirror acts as
// xor4; after 8-uniform, row_mirror acts as xor8. All lanes get the result.
static __device__ __forceinline__ float dpp_max16(float x) {
    float t;
    t = __int_as_float(__builtin_amdgcn_update_dpp(__float_as_int(x), __float_as_int(x), 0xB1, 0xF, 0xF, true));  // quad_perm [1,0,3,2]
    x = fmaxf(x, t);
    t = __int_as_float(__builtin_amdgcn_update_dpp(__float_as_int(x), __float_as_int(x), 0x4E, 0xF, 0xF, true));  // quad_perm [2,3,0,1]
    x = fmaxf(x, t);
    t = __int_as_float(__builtin_amdgcn_update_dpp(__float_as_int(x), __float_as_int(x), 0x141, 0xF, 0xF, true)); // row_half_mirror
    x = fmaxf(x, t);
    t = __int_as_float(__builtin_amdgcn_update_dpp(__float_as_int(x), __float_as_int(x), 0x140, 0xF, 0xF, true)); // row_mirror
    x = fmaxf(x, t);
    return x;
}

static __device__ __forceinline__ float dpp_sum16(float x) {
    float t;
    t = __int_as_float(__builtin_amdgcn_update_dpp(__float_as_int(x), __float_as_int(x), 0xB1, 0xF, 0xF, true));
    x += t;
    t = __int_as_float(__builtin_amdgcn_update_dpp(__float_as_int(x), __float_as_int(x), 0x4E, 0xF, 0xF, true));
    x += t;
    t = __int_as_float(__builtin_amdgcn_update_dpp(__float_as_int(x), __float_as_int(x), 0x141, 0xF, 0xF, true));
    x += t;
    t = __int_as_float(__builtin_amdgcn_update_dpp(__float_as_int(x), __float_as_int(x), 0x140, 0xF, 0xF, true));
    x += t;
    return x;
}

// Prologue: qkv_w fp32 [k=256][col=768] -> Wt bf16 [col=768][k=256] in d_ws.
__global__ void wt_transpose(const float* __restrict__ w, unsigned short* __restrict__ wt) {
    int col = blockIdx.x;      // 0..767
    int k   = threadIdx.x;     // 0..255
    float v = w[k * 768 + col];
    unsigned u = __float_as_uint(v);
    u = (u + 0x7fffu + ((u >> 16) & 1u)) >> 16;
    wt[col * 256 + k] = (unsigned short)u;
}

__global__ __launch_bounds__(512, 4) void swin_kernel(
    const float* __restrict__ x,            // (32,256,64,64)
    const unsigned short* __restrict__ wt,  // bf16 (768,256) transposed weights
    const float* __restrict__ qkv_b,        // (768,)
    const float* __restrict__ tbl,          // (225,8) rel-pos bias table
    float* __restrict__ out)                // (32,256,64,64)
{
    // LDS layout (bytes), total 80384 (2 blocks/CU of 160K):
    //   w_s : 0      .. 50688   (96 x 264 bf16)  weights for one head (shared)
    //   per window win (win*14848 after w_s):
    //     q_s : 50688+  (64 x 40 bf16)
    //     k_s : +5120   (64 x 40 bf16)
    //     vt_s: +10240  (32 x 72 bf16)  V transposed [hd][token]
    //   aliases into w_s, per window (win*17664):
    //     p_s : +0      (64 x 72 bf16)  softmax probs
    //     o_s : +9216   (64 x 33 f32)   PV output staging
    __shared__ char smem[80384];
    unsigned short* w_s = (unsigned short*)(smem);

    const int tid  = threadIdx.x;
    const int wave = tid >> 6;
    const int lane = tid & 63;
    const int ln   = lane & 15;
    const int quad = lane >> 4;
    const int win  = wave >> 2;     // which of the 2 windows
    const int wv   = wave & 3;      // wave-within-window

    const int blk = blockIdx.x;     // 0..1023
    const int b   = blk >> 5;       // image
    const int wh  = (blk >> 2) & 7; // window row
    const int wp  = blk & 3;        // window-pair col
    const int ww  = wp * 2 + win;   // window col for THIS thread's window

    unsigned short* q_s  = (unsigned short*)(smem + 50688 + win * 14848);
    unsigned short* k_s  = (unsigned short*)(smem + 50688 + win * 14848 + 5120);
    unsigned short* vt_s = (unsigned short*)(smem + 50688 + win * 14848 + 10240);
    unsigned short* p_s  = (unsigned short*)(smem + win * 17664);
    float*          o_s  = (float*)(smem + win * 17664 + 9216);

    // ---- A fragments: this wave's 16 tokens x 256 channels, bf16, in regs.
    // A[m=ln][k=quad*8+j]; token = wv*16 + ln. Read once, reuse 8 heads.
    const int t_a  = wv * 16 + ln;
    const int ti_a = t_a >> 3, tj_a = t_a & 7;
    const int si = (wh * 8 + ti_a + 4) & 63;   // roll(-SHIFT) source row
    const int sj = (ww * 8 + tj_a + 4) & 63;
    const float* xb = x + ((size_t)b * 256) * 4096 + si * 64 + sj;
    short8 afrag[8];
    #pragma unroll
    for (int ks = 0; ks < 8; ++ks) {
        #pragma unroll
        for (int j = 0; j < 8; ++j) {
            int c = ks * 32 + quad * 8 + j;
            afrag[ks][j] = f2bf(xb[(size_t)c * 4096]);
        }
    }

    const int row0 = wv * 16 + quad * 4;   // C/D layout: row = quad*4+reg

    // ---- hoist shift-mask bits and rel-pos indices out of the head loop.
    // mmask bit (nt*4+r) = masked; idxp[nt] = 4 byte-packed rel indices.
    unsigned mmask = 0;
    unsigned idxp[4];
    #pragma unroll
    for (int nt = 0; nt < 4; ++nt) {
        int tk = nt * 16 + ln;
        int tik = tk >> 3, tjk = tk & 7;
        int cntk = region(wh * 8 + tik) * 3 + region(ww * 8 + tjk);
        unsigned pk = 0;
        #pragma unroll
        for (int r = 0; r < 4; ++r) {
            int tq = row0 + r;
            int tiq = tq >> 3, tjq = tq & 7;
            int idx = (tiq - tik + 7) * 15 + (tjq - tjk + 7);   // 0..224
            pk |= (unsigned)idx << (8 * r);
            int cntq = region(wh * 8 + tiq) * 3 + region(ww * 8 + tjq);
            if (cntq != cntk) mmask |= 1u << (nt * 4 + r);
        }
        idxp[nt] = pk;
    }

    for (int h = 0; h < 8; ++h) {
        barrier_lds();   // protect w_s/p_s/o_s from previous phase readers

        // ---- stage 96 weight cols (q|k|v of head h) into w_s[col][k], padded.
        // 512 threads -> 6 iters (was 12 with 256 threads).
        #pragma unroll
        for (int i = 0; i < 6; ++i) {
            int idx = i * 512 + tid;              // 0..3071
            int cl  = idx >> 5;                   // local col 0..95
            int ch  = idx & 31;                   // k-chunk (8 elems)
            int col = ((cl >> 5) << 8) + (h << 5) + (cl & 31);  // global col
            short8 wv8 = *(const short8*)(wt + col * 256 + ch * 8);
            *(short8*)(w_s + cl * 264 + ch * 8) = wv8;
        }
        barrier_lds();

        // ---- GEMM1: (64 tok x 256) @ (256 x 96) -> QKV of head h (per window)
        f32x4 acc[6];
        #pragma unroll
        for (int jt = 0; jt < 6; ++jt) acc[jt] = (f32x4){0.f, 0.f, 0.f, 0.f};
        #pragma unroll
        for (int ks = 0; ks < 8; ++ks) {
            short8 a = afrag[ks];
            #pragma unroll
            for (int jt = 0; jt < 6; ++jt) {
                short8 bb = *(const short8*)(w_s + (jt * 16 + ln) * 264 + ks * 32 + quad * 8);
                acc[jt] = __builtin_amdgcn_mfma_f32_16x16x32_bf16(a, bb, acc[jt], 0, 0, 0);
            }
        }
        // epilogue: +bias; q scaled; q/k row-major, v transposed
        #pragma unroll
        for (int jt = 0; jt < 6; ++jt) {
            int colL = jt * 16 + ln;
            int seg  = colL >> 5;        // 0=q 1=k 2=v (uniform per jt)
            int cc   = colL & 31;
            float bias = qkv_b[(seg << 8) + (h << 5) + cc];
            #pragma unroll
            for (int r = 0; r < 4; ++r) {
                float v = acc[jt][r] + bias;
                int tok = row0 + r;
                if (seg == 0)      q_s[tok * 40 + cc] = (unsigned short)f2bf(v * 0.17677669529663689f);
                else if (seg == 1) k_s[tok * 40 + cc] = (unsigned short)f2bf(v);
                else               vt_s[cc * 72 + tok] = (unsigned short)f2bf(v);
            }
        }
        barrier_lds();

        // ---- GEMM2: S = q @ k^T  (wave's 16 q-rows x all 64 k-cols), K=32
        short8 aq = *(const short8*)(q_s + (wv * 16 + ln) * 40 + quad * 8);
        f32x4 sacc[4];
        #pragma unroll
        for (int nt = 0; nt < 4; ++nt) {
            short8 bk = *(const short8*)(k_s + (nt * 16 + ln) * 40 + quad * 8);
            f32x4 z = (f32x4){0.f, 0.f, 0.f, 0.f};
            sacc[nt] = __builtin_amdgcn_mfma_f32_16x16x32_bf16(aq, bk, z, 0, 0, 0);
        }
        // bias + shift-mask from precomputed idx/mask words
        float sv[4][4];
        #pragma unroll
        for (int nt = 0; nt < 4; ++nt) {
            #pragma unroll
            for (int r = 0; r < 4; ++r) {
                int idx = (idxp[nt] >> (8 * r)) & 255;
                float s = sacc[nt][r] + tbl[idx * 8 + h];
                s += ((mmask >> (nt * 4 + r)) & 1) ? -100.0f : 0.0f;
                sv[nt][r] = s;
            }
        }
        // softmax: row's 64 values = 16 lanes (this quad) x 4 nt-accums.
        // DPP butterfly (VALU pipe) instead of ds_bpermute shuffles.
        #pragma unroll
        for (int r = 0; r < 4; ++r) {
            float m = fmaxf(fmaxf(sv[0][r], sv[1][r]), fmaxf(sv[2][r], sv[3][r]));
            m = dpp_max16(m);
            float p0 = __expf(sv[0][r] - m);
            float p1 = __expf(sv[1][r] - m);
            float p2 = __expf(sv[2][r] - m);
            float p3 = __expf(sv[3][r] - m);
            float ssum = dpp_sum16(p0 + p1 + p2 + p3);
            float inv = __builtin_amdgcn_rcpf(ssum);
            int pr = (row0 + r) * 72;
            p_s[pr +      ln] = (unsigned short)f2bf(p0 * inv);
            p_s[pr + 16 + ln] = (unsigned short)f2bf(p1 * inv);
            p_s[pr + 32 + ln] = (unsigned short)f2bf(p2 * inv);
            p_s[pr + 48 + ln] = (unsigned short)f2bf(p3 * inv);
        }

        // ---- PV: O = P @ V  (16 rows x 32 hd, K=64). Same-wave LDS in-order
        // makes p_s write->read safe without a barrier (rows are wave-private).
        f32x4 oacc[2];
        oacc[0] = (f32x4){0.f, 0.f, 0.f, 0.f};
        oacc[1] = (f32x4){0.f, 0.f, 0.f, 0.f};
        #pragma unroll
        for (int ks = 0; ks < 2; ++ks) {
            short8 ap = *(const short8*)(p_s + (wv * 16 + ln) * 72 + ks * 32 + quad * 8);
            #pragma unroll
            for (int nt = 0; nt < 2; ++nt) {
                short8 bv = *(const short8*)(vt_s + (nt * 16 + ln) * 72 + ks * 32 + quad * 8);
                oacc[nt] = __builtin_amdgcn_mfma_f32_16x16x32_bf16(ap, bv, oacc[nt], 0, 0, 0);
            }
        }
        #pragma unroll
        for (int nt = 0; nt < 2; ++nt)
            #pragma unroll
            for (int r = 0; r < 4; ++r)
                o_s[(row0 + r) * 33 + nt * 16 + ln] = oacc[nt][r];
        barrier_lds();

        // ---- output: per-window 256 threads; thread = (ti2, hd); two float4
        // stores with the +SHIFT roll folded into addresses. Paired windows
        // (ww even/odd) write adjacent 32B halves of the same 64B lines.
        {
            int tl  = tid & 255;
            int cl  = tl & 31;           // hd
            int ti2 = tl >> 5;           // 0..7
            f32x4 v0, v1;
            #pragma unroll
            for (int tj = 0; tj < 4; ++tj) v0[tj] = o_s[(ti2 * 8 + tj) * 33 + cl];
            #pragma unroll
            for (int tj = 0; tj < 4; ++tj) v1[tj] = o_s[(ti2 * 8 + 4 + tj) * 33 + cl];
            int c  = (h << 5) + cl;
            int di = (wh * 8 + ti2 + 4) & 63;
            float* op = out + ((size_t)(b * 256 + c)) * 4096 + di * 64;
            *(f32x4*)(op + (ww * 8 + 4))        = v0;
            *(f32x4*)(op + ((ww * 8 + 8) & 63)) = v1;
        }
    }
}

extern "C" void kernel_launch(void* const* d_in, const int* in_sizes, int n_in,
                              void* d_out, int out_size, void* d_ws, size_t ws_size,
                              hipStream_t stream) {
    const float* x      = (const float*)d_in[0];
    const float* qkv_w  = (const float*)d_in[1];
    const float* qkv_b  = (const float*)d_in[2];
    const float* tbl    = (const float*)d_in[3];
    float* out          = (float*)d_out;
    unsigned short* Wt  = (unsigned short*)d_ws;   // needs 768*256*2 = 393216 B

    wt_transpose<<<dim3(768), dim3(256), 0, stream>>>(qkv_w, Wt);
    swin_kernel<<<dim3(1024), dim3(512), 0, stream>>>(x, Wt, qkv_b, tbl, out);
}